// Round 2
// baseline (1262.371 us; speedup 1.0000x reference)
//
#include <hip/hip_runtime.h>
#include <stdint.h>

// ---------------------------------------------------------------------------
// BGCGRU on MI355X: all heavy ops as bf16 MFMA NT-GEMMs (fp32 accumulate).
//   aggregation  C[m,f] = sum_n S[m,n]   * X[f,n]   (X spatial-contiguous)
//   projection   C[c,n] = sum_f W^T[c,f] * Y[n,f]   (Y feature-contiguous)
// Spatial dims padded: N 2000->2048, E 4000->4096. Feature 66 -> 96.
// Workspace: ~163 MB via 5 rotating 16MB slots (hand-checked liveness).
// ---------------------------------------------------------------------------

typedef __bf16 bf16;
typedef float  f32x4  __attribute__((ext_vector_type(4)));
typedef __bf16 bf16x8 __attribute__((ext_vector_type(8)));
typedef __bf16 bf16x4v __attribute__((ext_vector_type(4)));

#define DEVI __device__ __forceinline__

DEVI void gload16(const bf16* g, bf16* l) {
  __builtin_amdgcn_global_load_lds(
      (const __attribute__((address_space(1))) void*)g,
      (__attribute__((address_space(3))) void*)l, 16, 0, 0);
}

struct GemmArgs {
  const bf16* A; const bf16* B;
  bf16* Cn;   // normal write  [i][j], nullable
  bf16* Ct;   // transposed    [j][i], nullable
  int lda, ldb, ldcn, ldct, K;
  long sA, sB, sCn, sCt;  // per-batch element strides (0 = shared)
};

// m97-style 2-barrier NT GEMM. 4 waves (2x2), 16x16x32 bf16 MFMA, BK=32.
template<int BM, int BN>
__global__ __launch_bounds__(256) void gemm_nt(GemmArgs g) {
  constexpr int BK = 32;
  __shared__ bf16 Al[BM * BK];
  __shared__ bf16 Bl[BN * BK];
  const int tid  = threadIdx.x;
  const int wave = tid >> 6;
  const int lane = tid & 63;
  const int wm = (wave >> 1) * (BM / 2);
  const int wn = (wave & 1) * (BN / 2);
  constexpr int FM = BM / 32;
  constexpr int FN = BN / 32;
  const long zb = blockIdx.z;
  const bf16* Ab = g.A + zb * g.sA + (long)blockIdx.x * BM * g.lda;
  const bf16* Bb = g.B + zb * g.sB + (long)blockIdx.y * BN * g.ldb;
  f32x4 acc[FM][FN] = {};

  const int srow = tid >> 2;         // staging row 0..63
  const int sseg = (tid & 3) * 8;    // staging k-offset (elements)
  const int l15  = lane & 15;
  const int kof  = (lane >> 4) * 8;  // fragment k-offset (elements)

  for (int kt = 0; kt < g.K; kt += BK) {
    __syncthreads();
    #pragma unroll
    for (int c = 0; c < BM / 64; ++c)
      gload16(Ab + (long)(c * 64 + srow) * g.lda + kt + sseg,
              &Al[(c * 64 + wave * 16) * BK]);
    #pragma unroll
    for (int c = 0; c < BN / 64; ++c)
      gload16(Bb + (long)(c * 64 + srow) * g.ldb + kt + sseg,
              &Bl[(c * 64 + wave * 16) * BK]);
    __syncthreads();  // compiler drains vmcnt before s_barrier

    bf16x8 af[FM], bfr[FN];
    #pragma unroll
    for (int i = 0; i < FM; ++i)
      af[i] = *(const bf16x8*)&Al[(wm + i * 16 + l15) * BK + kof];
    #pragma unroll
    for (int j = 0; j < FN; ++j)
      bfr[j] = *(const bf16x8*)&Bl[(wn + j * 16 + l15) * BK + kof];
    #pragma unroll
    for (int i = 0; i < FM; ++i)
      #pragma unroll
      for (int j = 0; j < FN; ++j)
        acc[i][j] = __builtin_amdgcn_mfma_f32_16x16x32_bf16(af[i], bfr[j],
                                                            acc[i][j], 0, 0, 0);
  }

  // C/D layout (m89-verified): col = lane&15, row = (lane>>4)*4 + r.
  const int gm0 = blockIdx.x * BM + wm;
  const int gn0 = blockIdx.y * BN + wn;
  const int rowq = (lane >> 4) * 4;
  if (g.Cn) {
    bf16* Cn = g.Cn + zb * g.sCn;
    #pragma unroll
    for (int i = 0; i < FM; ++i)
      #pragma unroll
      for (int j = 0; j < FN; ++j) {
        const int m0 = gm0 + i * 16 + rowq;
        const int n  = gn0 + j * 16 + l15;
        #pragma unroll
        for (int r = 0; r < 4; ++r)
          Cn[(long)(m0 + r) * g.ldcn + n] = (bf16)acc[i][j][r];
      }
  }
  if (g.Ct) {
    bf16* Ct = g.Ct + zb * g.sCt;
    #pragma unroll
    for (int i = 0; i < FM; ++i)
      #pragma unroll
      for (int j = 0; j < FN; ++j) {
        const int m0 = gm0 + i * 16 + rowq;
        const int n  = gn0 + j * 16 + l15;
        bf16x4v v = { (bf16)acc[i][j][0], (bf16)acc[i][j][1],
                      (bf16)acc[i][j][2], (bf16)acc[i][j][3] };
        *(bf16x4v*)&Ct[(long)n * g.ldct + m0] = v;
      }
  }
}

// ---------------- prep / elementwise kernels -------------------------------

__global__ void cvt_pad(const float* in, int R, int C, bf16* out, int Cp) {
  const int r = blockIdx.y;
  const int c = blockIdx.x * blockDim.x + threadIdx.x;
  float v = (r < R && c < C) ? in[(long)r * C + c] : 0.f;
  out[(long)r * Cp + c] = (bf16)v;
}

__global__ void cvt_transpose(const float* in, int R, int C, bf16* out, int ldo) {
  __shared__ float t[64][65];
  const int n0 = blockIdx.x * 64;   // out cols  (= in rows)
  const int e0 = blockIdx.y * 64;   // out rows  (= in cols)
  const int tx = threadIdx.x, ty = threadIdx.y;
  for (int i = ty; i < 64; i += 4) {
    int r = n0 + i, c = e0 + tx;
    t[i][tx] = (r < R && c < C) ? in[(long)r * C + c] : 0.f;
  }
  __syncthreads();
  for (int i = ty; i < 64; i += 4)
    out[(long)(e0 + i) * ldo + n0 + tx] = (bf16)t[tx][i];
}

struct WPrep { const float* W; bf16* WT; int Fin, Fout, ldt; };
struct WAll {
  WPrep w[12];
  const float* aw1; const float* al1; float* s1;
  const float* aw2; const float* al2; float* s2;
};
__global__ void prep_weights(WAll a) {
  const int b = blockIdx.x;
  if (b < 12) {
    WPrep w = a.w[b];
    for (int i = threadIdx.x; i < w.Fout * w.ldt; i += blockDim.x) {
      int c = i / w.ldt, f = i % w.ldt;
      float v = (f < w.Fin) ? w.W[(long)f * w.Fout + c] : 0.f;
      w.WT[i] = (bf16)v;
    }
  } else if (b == 12) {
    for (int f = threadIdx.x; f < 128; f += blockDim.x) {
      float s = 0.f;
      for (int w = 0; w < 128; ++w) s += a.aw1[w * 128 + f] * a.al1[w];
      a.s1[f] = s;
    }
  } else {
    for (int f = threadIdx.x; f < 64; f += blockDim.x) {
      float s = 0.f;
      for (int w = 0; w < 64; ++w) s += a.aw2[w * 64 + f] * a.al2[w];
      a.s2[f] = s;
    }
  }
}

__global__ void build_tem1(const float* x, const float* h, bf16* tem) {
  const int b = blockIdx.y;
  const int i = blockIdx.x * blockDim.x + threadIdx.x;  // < 2048*96
  const int f = i % 96, n = i / 96;
  float v = 0.f;
  if (n < 2000 && f < 66) {
    if (f < 2) v = x[(long)b * 4000 + n * 2 + f];
    else       v = h[(long)b * 128000 + (long)n * 64 + (f - 2)];
  }
  tem[((long)b * 2048 + n) * 96 + f] = (bf16)v;
}

// tem2: f<2 -> x, f in [2,66) -> sigmoid(r)*h where r = fea[...,64+co] (bf16).
__global__ void build_tem2(const float* x, const float* h, const bf16* fea,
                           bf16* tem) {
  const int b = blockIdx.y;
  const int i = blockIdx.x * blockDim.x + threadIdx.x;
  const int f = i % 96, n = i / 96;
  float v = 0.f;
  if (n < 2000 && f < 66) {
    if (f < 2) v = x[(long)b * 4000 + n * 2 + f];
    else {
      int co = f - 2;
      float r = (float)fea[((long)b * 2048 + n) * 128 + 64 + co];
      v = (1.f / (1.f + expf(-r))) * h[(long)b * 128000 + (long)n * 64 + co];
    }
  }
  tem[((long)b * 2048 + n) * 96 + f] = (bf16)v;
}

// hop-attention: one wave per (b,n). logits_m = <hop_m, s>, softmax over 3.
template<int F>
__global__ void attention_k(const bf16* hop0, int ld0, const bf16* hop1, int ld1,
                            const bf16* hop2, int ld2, const float* s, bf16* fea) {
  const int nloc = blockIdx.x * 4 + (threadIdx.x >> 6);  // 0..2047
  const int b = blockIdx.y;
  const int lane = threadIdx.x & 63;
  const long bn = (long)b * 2048 + nloc;
  constexpr int NF = F / 64;
  float h0[NF], h1[NF], h2[NF];
  float d0 = 0.f, d1 = 0.f, d2 = 0.f;
  #pragma unroll
  for (int q = 0; q < NF; ++q) {
    int f = lane + q * 64;
    h0[q] = (float)hop0[bn * ld0 + f];
    h1[q] = (float)hop1[bn * ld1 + f];
    h2[q] = (float)hop2[bn * ld2 + f];
    float sv = s[f];
    d0 += h0[q] * sv; d1 += h1[q] * sv; d2 += h2[q] * sv;
  }
  #pragma unroll
  for (int o = 32; o; o >>= 1) {
    d0 += __shfl_xor(d0, o); d1 += __shfl_xor(d1, o); d2 += __shfl_xor(d2, o);
  }
  float mx = fmaxf(d0, fmaxf(d1, d2));
  float e0 = expf(d0 - mx), e1 = expf(d1 - mx), e2 = expf(d2 - mx);
  float inv = 1.f / (e0 + e1 + e2);
  e0 *= inv; e1 *= inv; e2 *= inv;
  #pragma unroll
  for (int q = 0; q < NF; ++q) {
    int f = lane + q * 64;
    fea[bn * F + f] = (bf16)(e0 * h0[q] + e1 * h1[q] + e2 * h2[q]);
  }
}

// new_h = sigmoid(z)*h + (1-sigmoid(z))*tanh(c)
__global__ void gru_out(const bf16* fea, const bf16* cc, const float* h,
                        float* out) {
  const int b = blockIdx.y;
  const int i = blockIdx.x * blockDim.x + threadIdx.x;  // < 2000*64
  const int co = i & 63, n = i >> 6;
  float z  = (float)fea[((long)b * 2048 + n) * 128 + co];
  float c  = (float)cc [((long)b * 2048 + n) * 64 + co];
  float hv = h[(long)b * 128000 + i];
  float zs = 1.f / (1.f + expf(-z));
  out[(long)b * 128000 + i] = zs * hv + (1.f - zs) * tanhf(c);
}

// Diagnostic: report ws budget (MB) through the absmax error if ws too small.
__global__ void ws_diag(float* out, int n, float v) {
  int i = blockIdx.x * blockDim.x + threadIdx.x;
  if (i < n) out[i] = v;
}

// ---------------------------------------------------------------------------

template<int BM, int BN>
static void launch_gemm(hipStream_t st, int Mt, int Nt,
                        const bf16* A, int lda, long sA,
                        const bf16* B, int ldb, long sB,
                        bf16* Cn, int ldcn, long sCn,
                        bf16* Ct, int ldct, long sCt, int K) {
  GemmArgs g{A, B, Cn, Ct, lda, ldb, ldcn, ldct, K, sA, sB, sCn, sCt};
  gemm_nt<BM, BN><<<dim3(Mt, Nt, 16), 256, 0, st>>>(g);
}

extern "C" void kernel_launch(void* const* d_in, const int* in_sizes, int n_in,
                              void* d_out, int out_size, void* d_ws, size_t ws_size,
                              hipStream_t stream) {
  const float* x    = (const float*)d_in[0];
  const float* hid  = (const float*)d_in[1];
  const float* S0   = (const float*)d_in[2];
  const float* S1   = (const float*)d_in[3];
  const float* M    = (const float*)d_in[4];

  char* base = (char*)d_ws;
  size_t off = 0;
  auto alloc = [&](size_t bytes) -> void* {
    void* r = base + off;
    off += (bytes + 255) & ~(size_t)255;
    return r;
  };

  // -------- fixed buffers --------
  bf16* S0b = (bf16*)alloc(2048ull * 2048 * 2);   //  8 MB
  bf16* S1b = (bf16*)alloc(4096ull * 4096 * 2);   // 32 MB
  bf16* Mb  = (bf16*)alloc(2048ull * 4096 * 2);   // 16 MB
  bf16* MTb = (bf16*)alloc(4096ull * 2048 * 2);   // 16 MB
  bf16* tem = (bf16*)alloc(16ull * 2048 * 96 * 2);   // 6.3 MB (tem1 & tem2)
  bf16* ccb = (bf16*)alloc(16ull * 2048 * 64 * 2);   // 4 MB

  static const int wd[12][3] = {
    {66,128,96},{66,128,96},{256,128,256},{256,128,256},{128,128,128},{128,128,128},
    {66, 64,96},{66, 64,96},{128, 64,128},{128, 64,128},{ 64, 64, 64},{ 64, 64, 64}};
  static const int wsrc[12] = {5,6,7,8,9,10, 13,14,15,16,17,18};
  bf16* Wt[12];
  for (int i = 0; i < 12; ++i) Wt[i] = (bf16*)alloc((size_t)wd[i][1] * wd[i][2] * 2);
  float* s1 = (float*)alloc(128 * 4);
  float* s2 = (float*)alloc(64 * 4);

  // -------- rotating 16MB slots --------
  const size_t SLOT = 16ull * 4096 * 128 * 2;  // 16 MB
  char* T0 = (char*)alloc(SLOT);
  char* T1 = (char*)alloc(SLOT);
  char* T2 = (char*)alloc(SLOT);
  char* T3 = (char*)alloc(SLOT);
  char* T4 = (char*)alloc(SLOT);

  if (off > ws_size) {  // budget diagnostic: absmax ~= ws_size in MB
    ws_diag<<<4, 256, 0, stream>>>((float*)d_out, 1024, (float)(ws_size >> 20));
    return;
  }

  // g1 slot assignment (liveness-checked):
  bf16* xWb   = (bf16*)T0;               // 8MB   steps 1-3
  bf16* xW0   = (bf16*)(T0 + 8388608);   // 8MB   steps 2-4
  bf16* eg0   = (bf16*)T1;               // 16MB  3-5
  bf16* cat1  = (bf16*)T2;               // 16MB  4-attn
  bf16* eg0p  = (bf16*)T3;               // 16MB  5-6
  bf16* eg1nf = (bf16*)T4;               // 16MB  6-10
  bf16* eg1fn = (bf16*)T1;               // 16MB  6-7
  bf16* cp1   = (bf16*)T0;               // 8MB   8-9
  bf16* cat2  = (bf16*)T3;               // 16MB  9-attn
  bf16* eg1p  = (bf16*)T1;               // 16MB  10-11
  bf16* eg2fn = (bf16*)T0;               // 16MB  11-12
  bf16* cp2   = (bf16*)T1;               // 8MB   13-14
  bf16* hop2  = (bf16*)(T1 + 8388608);   // 8MB   14-attn
  bf16* feab  = (bf16*)T4;               // 8MB   attn-end (eg1nf dead)

  // ---- prep ----
  cvt_pad<<<dim3(8, 2048), 256, 0, stream>>>(S0, 2000, 2000, S0b, 2048);
  cvt_pad<<<dim3(16, 4096), 256, 0, stream>>>(S1, 4000, 4000, S1b, 4096);
  cvt_pad<<<dim3(16, 2048), 256, 0, stream>>>(M, 2000, 4000, Mb, 4096);
  cvt_transpose<<<dim3(32, 64), dim3(64, 4), 0, stream>>>(M, 2000, 4000, MTb, 2048);
  WAll wa;
  for (int i = 0; i < 12; ++i)
    wa.w[i] = WPrep{(const float*)d_in[wsrc[i]], Wt[i], wd[i][0], wd[i][1], wd[i][2]};
  wa.aw1 = (const float*)d_in[11]; wa.al1 = (const float*)d_in[12]; wa.s1 = s1;
  wa.aw2 = (const float*)d_in[19]; wa.al2 = (const float*)d_in[20]; wa.s2 = s2;
  prep_weights<<<14, 256, 0, stream>>>(wa);
  build_tem1<<<dim3(768, 16), 256, 0, stream>>>(x, hid, tem);

  // ---- g1 (F = 128) ----
  launch_gemm<128,128>(stream, 1,16, Wt[0],96,0,  tem,96,2048L*96,   xWb,2048,128L*2048, nullptr,0,0, 96);
  launch_gemm<128,128>(stream, 1,16, Wt[1],96,0,  tem,96,2048L*96,   xW0,2048,128L*2048, nullptr,0,0, 96);
  launch_gemm<128,128>(stream, 32,1, MTb,2048,0,  xWb,2048,128L*2048, eg0,128,4096L*128, nullptr,0,0, 2048);
  launch_gemm<128,128>(stream, 16,1, S0b,2048,0,  xW0,2048,128L*2048, cat1,256,2048L*256, nullptr,0,0, 2048);
  launch_gemm<128,128>(stream, 1,32, Wt[4],128,0, eg0,128,4096L*128, eg0p,4096,128L*4096, nullptr,0,0, 128);
  launch_gemm<128,128>(stream, 32,1, S1b,4096,0,  eg0p,4096,128L*4096, eg1nf,128,4096L*128, eg1fn,4096,128L*4096, 4096);
  launch_gemm<128,128>(stream, 16,1, Mb,4096,0,   eg1fn,4096,128L*4096, cat1+128,256,2048L*256, nullptr,0,0, 4096);
  launch_gemm<128,128>(stream, 1,16, Wt[2],256,0, cat1,256,2048L*256, cp1,2048,128L*2048, nullptr,0,0, 256);
  launch_gemm<128,128>(stream, 16,1, S0b,2048,0,  cp1,2048,128L*2048, cat2,256,2048L*256, nullptr,0,0, 2048);
  launch_gemm<128,128>(stream, 1,32, Wt[5],128,0, eg1nf,128,4096L*128, eg1p,4096,128L*4096, nullptr,0,0, 128);
  launch_gemm<128,128>(stream, 32,1, S1b,4096,0,  eg1p,4096,128L*4096, nullptr,0,0, eg2fn,4096,128L*4096, 4096);
  launch_gemm<128,128>(stream, 16,1, Mb,4096,0,   eg2fn,4096,128L*4096, cat2+128,256,2048L*256, nullptr,0,0, 4096);
  launch_gemm<128,128>(stream, 1,16, Wt[3],256,0, cat2,256,2048L*256, cp2,2048,128L*2048, nullptr,0,0, 256);
  launch_gemm<128,128>(stream, 16,1, S0b,2048,0,  cp2,2048,128L*2048, hop2,128,2048L*128, nullptr,0,0, 2048);
  attention_k<128><<<dim3(512, 16), 256, 0, stream>>>(cat1,256, cat2,256, hop2,128, s1, feab);
  build_tem2<<<dim3(768, 16), 256, 0, stream>>>(x, hid, feab, tem);

  // g2 slot assignment (fea stays live at T4 low half):
  bf16* xWb2  = (bf16*)T0;               // 4MB
  bf16* xW02  = (bf16*)(T0 + 4194304);   // 4MB
  bf16* eg0_2   = (bf16*)T1;             // 8MB
  bf16* cat1_2  = (bf16*)T2;             // 8MB
  bf16* eg0p_2  = (bf16*)T3;             // 8MB
  bf16* eg1nf_2 = (bf16*)(T4 + 8388608); // 8MB (T4 hi; fea in T4 lo)
  bf16* eg1fn_2 = (bf16*)T1;             // 8MB
  bf16* cp1_2   = (bf16*)T0;             // 4MB
  bf16* cat2_2  = (bf16*)T3;             // 8MB
  bf16* eg1p_2  = (bf16*)T1;             // 8MB
  bf16* eg2fn_2 = (bf16*)T0;             // 8MB
  bf16* cp2_2   = (bf16*)T1;             // 4MB
  bf16* hop2_2  = (bf16*)(T1 + 8388608); // 4MB

  // ---- g2 (F = 64) ----
  launch_gemm<64,128>(stream, 1,16, Wt[6],96,0,  tem,96,2048L*96,   xWb2,2048,64L*2048, nullptr,0,0, 96);
  launch_gemm<64,128>(stream, 1,16, Wt[7],96,0,  tem,96,2048L*96,   xW02,2048,64L*2048, nullptr,0,0, 96);
  launch_gemm<128,64>(stream, 32,1, MTb,2048,0,  xWb2,2048,64L*2048, eg0_2,64,4096L*64, nullptr,0,0, 2048);
  launch_gemm<128,64>(stream, 16,1, S0b,2048,0,  xW02,2048,64L*2048, cat1_2,128,2048L*128, nullptr,0,0, 2048);
  launch_gemm<64,128>(stream, 1,32, Wt[10],64,0, eg0_2,64,4096L*64, eg0p_2,4096,64L*4096, nullptr,0,0, 64);
  launch_gemm<128,64>(stream, 32,1, S1b,4096,0,  eg0p_2,4096,64L*4096, eg1nf_2,64,4096L*64, eg1fn_2,4096,64L*4096, 4096);
  launch_gemm<128,64>(stream, 16,1, Mb,4096,0,   eg1fn_2,4096,64L*4096, cat1_2+64,128,2048L*128, nullptr,0,0, 4096);
  launch_gemm<64,128>(stream, 1,16, Wt[8],128,0, cat1_2,128,2048L*128, cp1_2,2048,64L*2048, nullptr,0,0, 128);
  launch_gemm<128,64>(stream, 16,1, S0b,2048,0,  cp1_2,2048,64L*2048, cat2_2,128,2048L*128, nullptr,0,0, 2048);
  launch_gemm<64,128>(stream, 1,32, Wt[11],64,0, eg1nf_2,64,4096L*64, eg1p_2,4096,64L*4096, nullptr,0,0, 64);
  launch_gemm<128,64>(stream, 32,1, S1b,4096,0,  eg1p_2,4096,64L*4096, nullptr,0,0, eg2fn_2,4096,64L*4096, 4096);
  launch_gemm<128,64>(stream, 16,1, Mb,4096,0,   eg2fn_2,4096,64L*4096, cat2_2+64,128,2048L*128, nullptr,0,0, 4096);
  launch_gemm<64,128>(stream, 1,16, Wt[9],128,0, cat2_2,128,2048L*128, cp2_2,2048,64L*2048, nullptr,0,0, 128);
  launch_gemm<128,64>(stream, 16,1, S0b,2048,0,  cp2_2,2048,64L*2048, hop2_2,64,2048L*64, nullptr,0,0, 2048);
  attention_k<64><<<dim3(512, 16), 256, 0, stream>>>(cat1_2,128, cat2_2,128, hop2_2,64, s2, ccb);

  gru_out<<<dim3(500, 16), 256, 0, stream>>>(feab, ccb, hid, (float*)d_out);
}

// Round 3
// 894.793 us; speedup vs baseline: 1.4108x; 1.4108x over previous
//
#include <hip/hip_runtime.h>
#include <stdint.h>

// ---------------------------------------------------------------------------
// BGCGRU on MI355X: all heavy ops as bf16 MFMA NT-GEMMs (fp32 accumulate).
//   aggregation  C[m,f] = sum_n S[m,n]   * X[f,n]   (X spatial-contiguous)
//   projection   C[c,n] = sum_f W^T[c,f] * Y[n,f]   (Y feature-contiguous)
// Round 3: double-buffered prefetch K-loop (stage t+1 before compute t),
// LDS XOR bank-swizzle (both-sides: pre-swizzled global source + swizzled
// read), independent GEMMs merged into multi-task launches.
// ---------------------------------------------------------------------------

typedef __bf16 bf16;
typedef float  f32x4  __attribute__((ext_vector_type(4)));
typedef __bf16 bf16x8 __attribute__((ext_vector_type(8)));
typedef __bf16 bf16x4v __attribute__((ext_vector_type(4)));

#define DEVI __device__ __forceinline__

DEVI void gload16(const bf16* g, bf16* l) {
  __builtin_amdgcn_global_load_lds(
      (const __attribute__((address_space(1))) void*)g,
      (__attribute__((address_space(3))) void*)l, 16, 0, 0);
}

struct GemmArgs {
  const bf16* A; const bf16* B;
  bf16* Cn;   // normal write  [i][j], nullable
  bf16* Ct;   // transposed    [j][i], nullable
  int lda, ldb, ldcn, ldct, K;
  long sA, sB, sCn, sCt;  // per-batch element strides
};

struct TaskDesc { GemmArgs g; int kind, gx, gy, blk0, nblk; };
struct MultiArgs { TaskDesc t[2]; int nt; };

// Double-buffered 1-barrier-per-iter NT GEMM body. 4 waves (2x2),
// 16x16x32 bf16 MFMA, BK=32. LDS rows are 64B; XOR swizzle spreads the
// 16-lane column reads across all 8 16B-slots (2-way residual = free).
template<int BM, int BN>
DEVI void gemm_body(const GemmArgs& g, int bx, int by, int bz,
                    bf16* Abuf, bf16* Bbuf) {
  constexpr int BK = 32;
  const int tid  = threadIdx.x;
  const int wave = tid >> 6;
  const int lane = tid & 63;
  const int wm = (wave >> 1) * (BM / 2);
  const int wn = (wave & 1) * (BN / 2);
  constexpr int FM = BM / 32;
  constexpr int FN = BN / 32;
  const bf16* Ab = g.A + (long)bz * g.sA + (long)bx * BM * g.lda;
  const bf16* Bb = g.B + (long)bz * g.sB + (long)by * BN * g.ldb;
  f32x4 acc[FM][FN] = {};

  const int srow = tid >> 2;                                // staging row
  const int sseg = ((lane & 3) ^ ((lane >> 3) & 3)) * 8;    // swz source seg
  const int l15  = lane & 15;
  const int kof  = ((lane >> 4) ^ ((lane >> 1) & 3)) * 8;   // swz read seg

  auto stage = [&](int buf, int kt) {
    #pragma unroll
    for (int c = 0; c < BM / 64; ++c)
      gload16(Ab + (long)(c * 64 + srow) * g.lda + kt + sseg,
              &Abuf[buf * (BM * BK) + (c * 64 + wave * 16) * BK]);
    #pragma unroll
    for (int c = 0; c < BN / 64; ++c)
      gload16(Bb + (long)(c * 64 + srow) * g.ldb + kt + sseg,
              &Bbuf[buf * (BN * BK) + (c * 64 + wave * 16) * BK]);
  };

  stage(0, 0);
  __syncthreads();                 // vmcnt(0)+barrier: tile0 resident
  int cur = 0;
  for (int kt = 0; kt < g.K; kt += BK) {
    if (kt + BK < g.K) stage(cur ^ 1, kt + BK);   // async, overlaps MFMA
    bf16x8 af[FM], bfr[FN];
    #pragma unroll
    for (int i = 0; i < FM; ++i)
      af[i] = *(const bf16x8*)&Abuf[cur * (BM * BK) + (wm + i * 16 + l15) * BK + kof];
    #pragma unroll
    for (int j = 0; j < FN; ++j)
      bfr[j] = *(const bf16x8*)&Bbuf[cur * (BN * BK) + (wn + j * 16 + l15) * BK + kof];
    #pragma unroll
    for (int i = 0; i < FM; ++i)
      #pragma unroll
      for (int j = 0; j < FN; ++j)
        acc[i][j] = __builtin_amdgcn_mfma_f32_16x16x32_bf16(af[i], bfr[j],
                                                            acc[i][j], 0, 0, 0);
    __syncthreads();               // drains staging vmcnt + read lgkm
    cur ^= 1;
  }

  // C/D layout (m89-verified): col = lane&15, row = (lane>>4)*4 + r.
  const int gm0 = bx * BM + wm;
  const int gn0 = by * BN + wn;
  const int rowq = (lane >> 4) * 4;
  if (g.Cn) {
    bf16* Cn = g.Cn + (long)bz * g.sCn;
    #pragma unroll
    for (int i = 0; i < FM; ++i)
      #pragma unroll
      for (int j = 0; j < FN; ++j) {
        const int m0 = gm0 + i * 16 + rowq;
        const int n  = gn0 + j * 16 + l15;
        #pragma unroll
        for (int r = 0; r < 4; ++r)
          Cn[(long)(m0 + r) * g.ldcn + n] = (bf16)acc[i][j][r];
      }
  }
  if (g.Ct) {
    bf16* Ct = g.Ct + (long)bz * g.sCt;
    #pragma unroll
    for (int i = 0; i < FM; ++i)
      #pragma unroll
      for (int j = 0; j < FN; ++j) {
        const int m0 = gm0 + i * 16 + rowq;
        const int n  = gn0 + j * 16 + l15;
        bf16x4v v = { (bf16)acc[i][j][0], (bf16)acc[i][j][1],
                      (bf16)acc[i][j][2], (bf16)acc[i][j][3] };
        *(bf16x4v*)&Ct[(long)n * g.ldct + m0] = v;
      }
  }
}

__global__ __launch_bounds__(256) void gemm_multi(MultiArgs mu) {
  __shared__ bf16 smem[16384];     // 32 KB: 2 dbuf x (A 8K + B 8K elems max)
  bf16* Abuf = smem;
  bf16* Bbuf = smem + 8192;
  const int b = blockIdx.x;
  const int ti = (mu.nt > 1 && b >= mu.t[1].blk0) ? 1 : 0;
  const TaskDesc t = mu.t[ti];
  const int local = b - t.blk0;
  const int bx = local % t.gx;
  const int rem = local / t.gx;
  const int by = rem % t.gy;
  const int bz = rem / t.gy;
  if (t.kind == 0)      gemm_body<128, 128>(t.g, bx, by, bz, Abuf, Bbuf);
  else if (t.kind == 1) gemm_body<128,  64>(t.g, bx, by, bz, Abuf, Bbuf);
  else                  gemm_body< 64, 128>(t.g, bx, by, bz, Abuf, Bbuf);
}

// ---------------- prep / elementwise kernels -------------------------------

__global__ void cvt_pad(const float* in, int R, int C, bf16* out, int Cp) {
  const int r = blockIdx.y;
  const int c = blockIdx.x * blockDim.x + threadIdx.x;
  float v = (r < R && c < C) ? in[(long)r * C + c] : 0.f;
  out[(long)r * Cp + c] = (bf16)v;
}

__global__ void cvt_transpose(const float* in, int R, int C, bf16* out, int ldo) {
  __shared__ float t[64][65];
  const int n0 = blockIdx.x * 64;
  const int e0 = blockIdx.y * 64;
  const int tx = threadIdx.x, ty = threadIdx.y;
  for (int i = ty; i < 64; i += 4) {
    int r = n0 + i, c = e0 + tx;
    t[i][tx] = (r < R && c < C) ? in[(long)r * C + c] : 0.f;
  }
  __syncthreads();
  for (int i = ty; i < 64; i += 4)
    out[(long)(e0 + i) * ldo + n0 + tx] = (bf16)t[tx][i];
}

struct WPrep { const float* W; bf16* WT; int Fin, Fout, ldt; };
struct WAll {
  WPrep w[12];
  const float* aw1; const float* al1; float* s1;
  const float* aw2; const float* al2; float* s2;
};
__global__ void prep_weights(WAll a) {
  const int b = blockIdx.x;
  if (b < 12) {
    WPrep w = a.w[b];
    for (int i = threadIdx.x; i < w.Fout * w.ldt; i += blockDim.x) {
      int c = i / w.ldt, f = i % w.ldt;
      float v = (f < w.Fin) ? w.W[(long)f * w.Fout + c] : 0.f;
      w.WT[i] = (bf16)v;
    }
  } else if (b == 12) {
    for (int f = threadIdx.x; f < 128; f += blockDim.x) {
      float s = 0.f;
      for (int w = 0; w < 128; ++w) s += a.aw1[w * 128 + f] * a.al1[w];
      a.s1[f] = s;
    }
  } else {
    for (int f = threadIdx.x; f < 64; f += blockDim.x) {
      float s = 0.f;
      for (int w = 0; w < 64; ++w) s += a.aw2[w * 64 + f] * a.al2[w];
      a.s2[f] = s;
    }
  }
}

__global__ void build_tem1(const float* x, const float* h, bf16* tem) {
  const int b = blockIdx.y;
  const int i = blockIdx.x * blockDim.x + threadIdx.x;
  const int f = i % 96, n = i / 96;
  float v = 0.f;
  if (n < 2000 && f < 66) {
    if (f < 2) v = x[(long)b * 4000 + n * 2 + f];
    else       v = h[(long)b * 128000 + (long)n * 64 + (f - 2)];
  }
  tem[((long)b * 2048 + n) * 96 + f] = (bf16)v;
}

__global__ void build_tem2(const float* x, const float* h, const bf16* fea,
                           bf16* tem) {
  const int b = blockIdx.y;
  const int i = blockIdx.x * blockDim.x + threadIdx.x;
  const int f = i % 96, n = i / 96;
  float v = 0.f;
  if (n < 2000 && f < 66) {
    if (f < 2) v = x[(long)b * 4000 + n * 2 + f];
    else {
      int co = f - 2;
      float r = (float)fea[((long)b * 2048 + n) * 128 + 64 + co];
      v = (1.f / (1.f + expf(-r))) * h[(long)b * 128000 + (long)n * 64 + co];
    }
  }
  tem[((long)b * 2048 + n) * 96 + f] = (bf16)v;
}

template<int F>
__global__ void attention_k(const bf16* hop0, int ld0, const bf16* hop1, int ld1,
                            const bf16* hop2, int ld2, const float* s, bf16* fea) {
  const int nloc = blockIdx.x * 4 + (threadIdx.x >> 6);
  const int b = blockIdx.y;
  const int lane = threadIdx.x & 63;
  const long bn = (long)b * 2048 + nloc;
  constexpr int NF = F / 64;
  float h0[NF], h1[NF], h2[NF];
  float d0 = 0.f, d1 = 0.f, d2 = 0.f;
  #pragma unroll
  for (int q = 0; q < NF; ++q) {
    int f = lane + q * 64;
    h0[q] = (float)hop0[bn * ld0 + f];
    h1[q] = (float)hop1[bn * ld1 + f];
    h2[q] = (float)hop2[bn * ld2 + f];
    float sv = s[f];
    d0 += h0[q] * sv; d1 += h1[q] * sv; d2 += h2[q] * sv;
  }
  #pragma unroll
  for (int o = 32; o; o >>= 1) {
    d0 += __shfl_xor(d0, o); d1 += __shfl_xor(d1, o); d2 += __shfl_xor(d2, o);
  }
  float mx = fmaxf(d0, fmaxf(d1, d2));
  float e0 = expf(d0 - mx), e1 = expf(d1 - mx), e2 = expf(d2 - mx);
  float inv = 1.f / (e0 + e1 + e2);
  e0 *= inv; e1 *= inv; e2 *= inv;
  #pragma unroll
  for (int q = 0; q < NF; ++q) {
    int f = lane + q * 64;
    fea[bn * F + f] = (bf16)(e0 * h0[q] + e1 * h1[q] + e2 * h2[q]);
  }
}

__global__ void gru_out(const bf16* fea, const bf16* cc, const float* h,
                        float* out) {
  const int b = blockIdx.y;
  const int i = blockIdx.x * blockDim.x + threadIdx.x;
  const int co = i & 63, n = i >> 6;
  float z  = (float)fea[((long)b * 2048 + n) * 128 + co];
  float c  = (float)cc [((long)b * 2048 + n) * 64 + co];
  float hv = h[(long)b * 128000 + i];
  float zs = 1.f / (1.f + expf(-z));
  out[(long)b * 128000 + i] = zs * hv + (1.f - zs) * tanhf(c);
}

__global__ void ws_diag(float* out, int n, float v) {
  int i = blockIdx.x * blockDim.x + threadIdx.x;
  if (i < n) out[i] = v;
}

// ---------------------------------------------------------------------------

static TaskDesc TD(int kind, int gx, int gy, int gz,
                   const bf16* A, int lda, long sA,
                   const bf16* B, int ldb, long sB,
                   bf16* Cn, int ldcn, long sCn,
                   bf16* Ct, int ldct, long sCt, int K) {
  TaskDesc t;
  t.g = GemmArgs{A, B, Cn, Ct, lda, ldb, ldcn, ldct, K, sA, sB, sCn, sCt};
  t.kind = kind; t.gx = gx; t.gy = gy; t.blk0 = 0; t.nblk = gx * gy * gz;
  return t;
}
static void run1(hipStream_t st, TaskDesc a) {
  MultiArgs m; m.t[0] = a; m.t[0].blk0 = 0; m.nt = 1;
  gemm_multi<<<a.nblk, 256, 0, st>>>(m);
}
static void run2p(hipStream_t st, TaskDesc a, TaskDesc b) {
  MultiArgs m; m.t[0] = a; m.t[0].blk0 = 0;
  m.t[1] = b; m.t[1].blk0 = a.nblk; m.nt = 2;
  gemm_multi<<<a.nblk + b.nblk, 256, 0, st>>>(m);
}

extern "C" void kernel_launch(void* const* d_in, const int* in_sizes, int n_in,
                              void* d_out, int out_size, void* d_ws, size_t ws_size,
                              hipStream_t stream) {
  const float* x    = (const float*)d_in[0];
  const float* hid  = (const float*)d_in[1];
  const float* S0   = (const float*)d_in[2];
  const float* S1   = (const float*)d_in[3];
  const float* M    = (const float*)d_in[4];

  char* base = (char*)d_ws;
  size_t off = 0;
  auto alloc = [&](size_t bytes) -> void* {
    void* r = base + off;
    off += (bytes + 255) & ~(size_t)255;
    return r;
  };

  bf16* S0b = (bf16*)alloc(2048ull * 2048 * 2);
  bf16* S1b = (bf16*)alloc(4096ull * 4096 * 2);
  bf16* Mb  = (bf16*)alloc(2048ull * 4096 * 2);
  bf16* MTb = (bf16*)alloc(4096ull * 2048 * 2);
  bf16* tem = (bf16*)alloc(16ull * 2048 * 96 * 2);
  bf16* ccb = (bf16*)alloc(16ull * 2048 * 64 * 2);

  static const int wd[12][3] = {
    {66,128,96},{66,128,96},{256,128,256},{256,128,256},{128,128,128},{128,128,128},
    {66, 64,96},{66, 64,96},{128, 64,128},{128, 64,128},{ 64, 64, 64},{ 64, 64, 64}};
  static const int wsrc[12] = {5,6,7,8,9,10, 13,14,15,16,17,18};
  bf16* Wt[12];
  for (int i = 0; i < 12; ++i) Wt[i] = (bf16*)alloc((size_t)wd[i][1] * wd[i][2] * 2);
  float* s1 = (float*)alloc(128 * 4);
  float* s2 = (float*)alloc(64 * 4);

  const size_t SLOT = 16ull * 4096 * 128 * 2;  // 16 MB
  char* T0 = (char*)alloc(SLOT);
  char* T1 = (char*)alloc(SLOT);
  char* T2 = (char*)alloc(SLOT);
  char* T3 = (char*)alloc(SLOT);
  char* T4 = (char*)alloc(SLOT);

  if (off > ws_size) {
    ws_diag<<<4, 256, 0, stream>>>((float*)d_out, 1024, (float)(ws_size >> 20));
    return;
  }

  // g1 buffers (liveness-checked under merged schedule):
  bf16* xW    = (bf16*)T0;               // [z][256][2048]  G1-G2
  bf16* eg0   = (bf16*)T1;               // G2-G3
  bf16* cat1  = (bf16*)T2;               // G2-attn
  bf16* eg0p  = (bf16*)T3;               // G3-G4
  bf16* eg1nf = (bf16*)T4;               // G4-G5
  bf16* eg1fn = (bf16*)T0;               // G4-G5
  bf16* eg1p  = (bf16*)T3;               // G5-G6
  bf16* cp1   = (bf16*)T1;               // G6-G7
  bf16* eg2fn = (bf16*)T0;               // G6-G7
  bf16* cat2  = (bf16*)T3;               // G7-attn
  bf16* cp2   = (bf16*)T1;               // G8-G9
  bf16* hop2  = (bf16*)(T1 + 8388608);   // G9-attn
  bf16* feab  = (bf16*)T4;               // attn-gru_out (8MB lo)

  // ---- prep ----
  cvt_pad<<<dim3(8, 2048), 256, 0, stream>>>(S0, 2000, 2000, S0b, 2048);
  cvt_pad<<<dim3(16, 4096), 256, 0, stream>>>(S1, 4000, 4000, S1b, 4096);
  cvt_pad<<<dim3(16, 2048), 256, 0, stream>>>(M, 2000, 4000, Mb, 4096);
  cvt_transpose<<<dim3(32, 64), dim3(64, 4), 0, stream>>>(M, 2000, 4000, MTb, 2048);
  WAll wa;
  for (int i = 0; i < 12; ++i)
    wa.w[i] = WPrep{(const float*)d_in[wsrc[i]], Wt[i], wd[i][0], wd[i][1], wd[i][2]};
  wa.aw1 = (const float*)d_in[11]; wa.al1 = (const float*)d_in[12]; wa.s1 = s1;
  wa.aw2 = (const float*)d_in[19]; wa.al2 = (const float*)d_in[20]; wa.s2 = s2;
  prep_weights<<<14, 256, 0, stream>>>(wa);
  build_tem1<<<dim3(768, 16), 256, 0, stream>>>(x, hid, tem);

  // ---- g1 (F = 128) ----
  // G1: fused proj [Wt0;Wt1] (contiguous, M=256) -> xW[z][0:256][n]
  run1(stream, TD(0, 2,16,16, Wt[0],96,0, tem,96,2048L*96,
                  xW,2048,256L*2048, nullptr,0,0, 96));
  // G2: MT agg (xW lo) + S0 agg (xW hi)
  run2p(stream,
    TD(0, 32,1,16, MTb,2048,0, xW,2048,256L*2048, eg0,128,4096L*128, nullptr,0,0, 2048),
    TD(0, 16,1,16, S0b,2048,0, xW+128*2048,2048,256L*2048, cat1,256,2048L*256, nullptr,0,0, 2048));
  // G3: eg0 proj (Wt4)
  run1(stream, TD(0, 1,32,16, Wt[4],128,0, eg0,128,4096L*128,
                  eg0p,4096,128L*4096, nullptr,0,0, 128));
  // G4: S1 agg #1 (dual write)
  run1(stream, TD(0, 32,1,16, S1b,4096,0, eg0p,4096,128L*4096,
                  eg1nf,128,4096L*128, eg1fn,4096,128L*4096, 4096));
  // G5: M agg #1 + Wt5 proj
  run2p(stream,
    TD(0, 16,1,16, Mb,4096,0, eg1fn,4096,128L*4096, cat1+128,256,2048L*256, nullptr,0,0, 4096),
    TD(0, 1,32,16, Wt[5],128,0, eg1nf,128,4096L*128, eg1p,4096,128L*4096, nullptr,0,0, 128));
  // G6: Wt2 proj + S1 agg #2
  run2p(stream,
    TD(0, 1,16,16, Wt[2],256,0, cat1,256,2048L*256, cp1,2048,128L*2048, nullptr,0,0, 256),
    TD(0, 32,1,16, S1b,4096,0, eg1p,4096,128L*4096, nullptr,0,0, eg2fn,4096,128L*4096, 4096));
  // G7: S0 agg #2 + M agg #2
  run2p(stream,
    TD(0, 16,1,16, S0b,2048,0, cp1,2048,128L*2048, cat2,256,2048L*256, nullptr,0,0, 2048),
    TD(0, 16,1,16, Mb,4096,0, eg2fn,4096,128L*4096, cat2+128,256,2048L*256, nullptr,0,0, 4096));
  // G8: Wt3 proj
  run1(stream, TD(0, 1,16,16, Wt[3],256,0, cat2,256,2048L*256,
                  cp2,2048,128L*2048, nullptr,0,0, 256));
  // G9: S0 agg #3
  run1(stream, TD(0, 16,1,16, S0b,2048,0, cp2,2048,128L*2048,
                  hop2,128,2048L*128, nullptr,0,0, 2048));
  attention_k<128><<<dim3(512, 16), 256, 0, stream>>>(cat1,256, cat2,256, hop2,128, s1, feab);
  build_tem2<<<dim3(768, 16), 256, 0, stream>>>(x, hid, feab, tem);

  // g2 buffers (feab stays live at T4 lo):
  bf16* xW2     = (bf16*)T0;               // [z][128][2048]
  bf16* eg0_2   = (bf16*)T1;
  bf16* cat1_2  = (bf16*)T2;
  bf16* eg0p_2  = (bf16*)T3;
  bf16* eg1nf_2 = (bf16*)(T4 + 8388608);   // T4 hi
  bf16* eg1fn_2 = (bf16*)T0;
  bf16* eg1p_2  = (bf16*)T3;
  bf16* cp1_2   = (bf16*)T1;
  bf16* eg2fn_2 = (bf16*)T0;
  bf16* cat2_2  = (bf16*)T3;
  bf16* cp2_2   = (bf16*)T1;
  bf16* hop2_2  = (bf16*)(T1 + 4194304);

  // ---- g2 (F = 64) ----
  // H1: fused proj [Wt6;Wt7] (contiguous, M=128)
  run1(stream, TD(0, 1,16,16, Wt[6],96,0, tem,96,2048L*96,
                  xW2,2048,128L*2048, nullptr,0,0, 96));
  // H2: MT agg + S0 agg
  run2p(stream,
    TD(1, 32,1,16, MTb,2048,0, xW2,2048,128L*2048, eg0_2,64,4096L*64, nullptr,0,0, 2048),
    TD(1, 16,1,16, S0b,2048,0, xW2+64*2048,2048,128L*2048, cat1_2,128,2048L*128, nullptr,0,0, 2048));
  // H3: Wt10 proj
  run1(stream, TD(2, 1,32,16, Wt[10],64,0, eg0_2,64,4096L*64,
                  eg0p_2,4096,64L*4096, nullptr,0,0, 64));
  // H4: S1 agg #1
  run1(stream, TD(1, 32,1,16, S1b,4096,0, eg0p_2,4096,64L*4096,
                  eg1nf_2,64,4096L*64, eg1fn_2,4096,64L*4096, 4096));
  // H5: M agg #1 + Wt11 proj
  run2p(stream,
    TD(1, 16,1,16, Mb,4096,0, eg1fn_2,4096,64L*4096, cat1_2+64,128,2048L*128, nullptr,0,0, 4096),
    TD(2, 1,32,16, Wt[11],64,0, eg1nf_2,64,4096L*64, eg1p_2,4096,64L*4096, nullptr,0,0, 64));
  // H6: Wt8 proj + S1 agg #2
  run2p(stream,
    TD(2, 1,16,16, Wt[8],128,0, cat1_2,128,2048L*128, cp1_2,2048,64L*2048, nullptr,0,0, 128),
    TD(1, 32,1,16, S1b,4096,0, eg1p_2,4096,64L*4096, nullptr,0,0, eg2fn_2,4096,64L*4096, 4096));
  // H7: S0 agg #2 + M agg #2
  run2p(stream,
    TD(1, 16,1,16, S0b,2048,0, cp1_2,2048,64L*2048, cat2_2,128,2048L*128, nullptr,0,0, 2048),
    TD(1, 16,1,16, Mb,4096,0, eg2fn_2,4096,64L*4096, cat2_2+64,128,2048L*128, nullptr,0,0, 4096));
  // H8: Wt9 proj
  run1(stream, TD(2, 1,16,16, Wt[9],128,0, cat2_2,128,2048L*128,
                  cp2_2,2048,64L*2048, nullptr,0,0, 128));
  // H9: S0 agg #3
  run1(stream, TD(1, 16,1,16, S0b,2048,0, cp2_2,2048,64L*2048,
                  hop2_2,64,2048L*64, nullptr,0,0, 2048));
  attention_k<64><<<dim3(512, 16), 256, 0, stream>>>(cat1_2,128, cat2_2,128, hop2_2,64, s2, ccb);

  gru_out<<<dim3(500, 16), 256, 0, stream>>>(feab, ccb, hid, (float*)d_out);
}